// Round 1
// baseline (48.270 us; speedup 1.0000x reference)
//
#include <hip/hip_runtime.h>
#include <hip/hip_bf16.h>

// Problem: 4 embedding-table row gathers.
//   indices: rgap, sgap, pcount, prcount  int32 [128*500] = 64000 each
//   tables:  Wr, Ws, Wp, Wpr              f32   [100*256]
//   output:  concat of 4x [64000, 256] f32 = 65,536,000 floats (262 MB)
//
// Memory-bound on output writes. Strategy: each group of 64 consecutive
// threads (one wave) handles one output row per iteration; the row index
// load is wave-uniform (scalar), each lane stores one float4 (64 lanes x
// 16 B = 1 KiB per wave-store, perfectly coalesced). Grid-stride loop with
// ~2048 blocks (Guideline 11: cap blocks, stride the rest).

#define ROWS_PER_TABLE 64000        // B*S = 128*500
#define VEC4_PER_ROW   64           // 256 f32 = 64 float4
#define VEC4_PER_TABLE (ROWS_PER_TABLE * VEC4_PER_ROW)  // 4,096,000

__global__ __launch_bounds__(256) void gather4_kernel(
    const int* __restrict__ i0, const int* __restrict__ i1,
    const int* __restrict__ i2, const int* __restrict__ i3,
    const float4* __restrict__ w0, const float4* __restrict__ w1,
    const float4* __restrict__ w2, const float4* __restrict__ w3,
    float4* __restrict__ out)
{
    const int* idx[4] = {i0, i1, i2, i3};
    const float4* w[4] = {w0, w1, w2, w3};

    const long stride = (long)gridDim.x * blockDim.x;
    for (long j = (long)blockIdx.x * blockDim.x + threadIdx.x;
         j < (long)VEC4_PER_TABLE; j += stride) {
        const int r = (int)(j >> 6);   // row 0..63999 (wave-uniform: 64
                                       // consecutive threads share r)
        const int l = (int)(j & 63);   // float4 slot within the row
#pragma unroll
        for (int t = 0; t < 4; ++t) {
            const int id = idx[t][r];                    // scalar (uniform) load
            out[(long)t * VEC4_PER_TABLE + j] = w[t][id * VEC4_PER_ROW + l];
        }
    }
}

extern "C" void kernel_launch(void* const* d_in, const int* in_sizes, int n_in,
                              void* d_out, int out_size, void* d_ws, size_t ws_size,
                              hipStream_t stream) {
    const int* rgap    = (const int*)d_in[0];
    const int* sgap    = (const int*)d_in[1];
    const int* pcount  = (const int*)d_in[2];
    const int* prcount = (const int*)d_in[3];
    const float4* Wr  = (const float4*)d_in[4];
    const float4* Ws  = (const float4*)d_in[5];
    const float4* Wp  = (const float4*)d_in[6];
    const float4* Wpr = (const float4*)d_in[7];
    float4* out = (float4*)d_out;

    const int block = 256;
    const int grid  = 2048;   // 256 CU x 8 blocks/CU cap; grid-stride covers rest

    gather4_kernel<<<grid, block, 0, stream>>>(
        rgap, sgap, pcount, prcount, Wr, Ws, Wp, Wpr, out);
}